// Round 1
// baseline (247.154 us; speedup 1.0000x reference)
//
#include <hip/hip_runtime.h>

using i32x4 = __attribute__((ext_vector_type(4))) int;

#define DEVI static __device__ __forceinline__

DEVI void gload_lds16(const void* g, void* l) {
  __builtin_amdgcn_global_load_lds(
      (const __attribute__((address_space(1))) void*)g,
      (__attribute__((address_space(3))) void*)l, 16, 0, 0);
}

// ---------------- pack int32 weights -> int8 ----------------
__global__ void __launch_bounds__(256) pack_w_kernel(const int* __restrict__ w,
                                                     signed char* __restrict__ o,
                                                     int n4) {
  int stride = gridDim.x * blockDim.x;
  for (int i = blockIdx.x * blockDim.x + threadIdx.x; i < n4; i += stride) {
    int4 v = reinterpret_cast<const int4*>(w)[i];
    char4 c;
    c.x = (signed char)v.x;
    c.y = (signed char)v.y;
    c.z = (signed char)v.z;
    c.w = (signed char)v.w;
    reinterpret_cast<char4*>(o)[i] = c;
  }
}

// ---------------- quantize fp32 x -> int8 ----------------
__global__ void __launch_bounds__(256) quant_x_kernel(const float* __restrict__ x,
                                                      signed char* __restrict__ o,
                                                      const float* __restrict__ amax,
                                                      int n4) {
  const float s = 127.0f / amax[0];
  int stride = gridDim.x * blockDim.x;
  for (int i = blockIdx.x * blockDim.x + threadIdx.x; i < n4; i += stride) {
    float4 v = reinterpret_cast<const float4*>(x)[i];
    char4 c;
    float q;
    q = fminf(fmaxf(rintf(__fmul_rn(v.x, s)), -127.0f), 127.0f); c.x = (signed char)(int)q;
    q = fminf(fmaxf(rintf(__fmul_rn(v.y, s)), -127.0f), 127.0f); c.y = (signed char)(int)q;
    q = fminf(fmaxf(rintf(__fmul_rn(v.z, s)), -127.0f), 127.0f); c.z = (signed char)(int)q;
    q = fminf(fmaxf(rintf(__fmul_rn(v.w, s)), -127.0f), 127.0f); c.w = (signed char)(int)q;
    reinterpret_cast<char4*>(o)[i] = c;
  }
}

// ---------------- int8 GEMM, m97 structure ----------------
// A: [M,K] int8 row-major; W: [N,K] int8 row-major (i.e. B^T layout)
// out = dequant(A@W^T) + bias ; OUT_I8=1: relu + requant to int8; else fp32.
template <int OUT_I8>
__global__ void __launch_bounds__(256) gemm_i8_kernel(
    const signed char* __restrict__ A, const signed char* __restrict__ W,
    const int* __restrict__ bias, void* __restrict__ out, int M, int N, int K,
    const float* __restrict__ p_ain, const float* __restrict__ p_aw,
    const float* __restrict__ p_ab, const float* __restrict__ p_anext) {
  constexpr int BK = 64;
  __shared__ signed char As[128 * BK];
  __shared__ signed char Bs[128 * BK];

  const int tid = threadIdx.x;
  const int lane = tid & 63;
  const int wave = tid >> 6;
  const int wr = (wave >> 1) * 64;   // wave's row quadrant in 128x128 tile
  const int wc = (wave & 1) * 64;    // wave's col quadrant
  const int tileM = blockIdx.y * 128;
  const int tileN = blockIdx.x * 128;

  const signed char* Ab = A + (size_t)tileM * K;
  const signed char* Wb = W + (size_t)tileN * K;

  const int r = tid >> 2;            // staging row 0..63
  const int cb = (tid & 3) * 16;     // staging byte offset within 64B row

  i32x4 acc[4][4] = {};

  const int ro = lane & 15;          // fragment row within 16
  const int kq = (lane >> 4) * 16;   // 16B k-group offset

  for (int k0 = 0; k0 < K; k0 += BK) {
    // stage A-tile [128][64]B and W-tile [128][64]B, linear LDS layout
    gload_lds16(Ab + (size_t)r * K + (k0 + cb), As + tid * 16);
    gload_lds16(Ab + (size_t)(r + 64) * K + (k0 + cb), As + 4096 + tid * 16);
    gload_lds16(Wb + (size_t)r * K + (k0 + cb), Bs + tid * 16);
    gload_lds16(Wb + (size_t)(r + 64) * K + (k0 + cb), Bs + 4096 + tid * 16);
    __syncthreads();

    i32x4 af[4], bf[4];
#pragma unroll
    for (int m = 0; m < 4; ++m)
      af[m] = *reinterpret_cast<const i32x4*>(As + (wr + m * 16 + ro) * 64 + kq);
#pragma unroll
    for (int n = 0; n < 4; ++n)
      bf[n] = *reinterpret_cast<const i32x4*>(Bs + (wc + n * 16 + ro) * 64 + kq);
#pragma unroll
    for (int m = 0; m < 4; ++m)
#pragma unroll
      for (int n = 0; n < 4; ++n)
        acc[m][n] =
            __builtin_amdgcn_mfma_i32_16x16x64_i8(af[m], bf[n], acc[m][n], 0, 0, 0);
    __syncthreads();
  }

  // ---- epilogue: dequant + bias (+ relu + requant) ----
  const float s1 = __fmul_rn(p_aw[0], p_ain[0]) / 16129.0f;  // a_w*a_in/127^2
  const float s2 = p_ab[0] / 127.0f;                         // a_b/127
  float qs = 0.0f;
  if (OUT_I8) qs = 127.0f / p_anext[0];

  const int cl = lane & 15;
  const int rg = (lane >> 4) * 4;

#pragma unroll
  for (int m = 0; m < 4; ++m) {
#pragma unroll
    for (int n = 0; n < 4; ++n) {
      const int col = tileN + wc + n * 16 + cl;   // output feature
      const int row = tileM + wr + m * 16 + rg;   // batch row base
      const float bv = __fmul_rn((float)bias[col], s2);
#pragma unroll
      for (int i = 0; i < 4; ++i) {
        float y = __fadd_rn(__fmul_rn((float)acc[m][n][i], s1), bv);
        if (OUT_I8) {
          float rl = fmaxf(y, 0.0f);
          float q = fminf(rintf(__fmul_rn(rl, qs)), 127.0f);
          ((signed char*)out)[(size_t)(row + i) * N + col] = (signed char)(int)q;
        } else {
          ((float*)out)[(size_t)(row + i) * N + col] = y;
        }
      }
    }
  }
}

extern "C" void kernel_launch(void* const* d_in, const int* in_sizes, int n_in,
                              void* d_out, int out_size, void* d_ws, size_t ws_size,
                              hipStream_t stream) {
  const float* x = (const float*)d_in[0];
  const int* W0 = (const int*)d_in[1];
  const int* b0 = (const int*)d_in[2];
  const int* W2 = (const int*)d_in[3];
  const int* b2 = (const int*)d_in[4];
  const int* W4 = (const int*)d_in[5];
  const int* b4 = (const int*)d_in[6];
  const float* a0_in = (const float*)d_in[7];
  const float* a0_w = (const float*)d_in[8];
  const float* a0_b = (const float*)d_in[9];
  const float* a2_in = (const float*)d_in[10];
  const float* a2_w = (const float*)d_in[11];
  const float* a2_b = (const float*)d_in[12];
  const float* a4_in = (const float*)d_in[13];
  const float* a4_w = (const float*)d_in[14];
  const float* a4_b = (const float*)d_in[15];

  constexpr int Bb = 4096, DIN = 2048, H = 4096, DOUT = 2048;
  constexpr size_t MB = 1u << 20;

  char* ws = (char*)d_ws;
  // layout (56 MB total): xq2 aliases [xq0 + W0q], both dead after GEMM1
  signed char* xq0 = (signed char*)(ws);             //  8 MB  [0,8)
  signed char* xq2 = (signed char*)(ws);             // 16 MB  [0,16) (later)
  signed char* W0q = (signed char*)(ws + 8 * MB);    //  8 MB  [8,16)
  signed char* W2q = (signed char*)(ws + 16 * MB);   // 16 MB  [16,32)
  signed char* W4q = (signed char*)(ws + 32 * MB);   //  8 MB  [32,40)
  signed char* xq1 = (signed char*)(ws + 40 * MB);   // 16 MB  [40,56)

  pack_w_kernel<<<2048, 256, 0, stream>>>(W0, W0q, H * DIN / 4);
  pack_w_kernel<<<2048, 256, 0, stream>>>(W2, W2q, H * H / 4);
  pack_w_kernel<<<2048, 256, 0, stream>>>(W4, W4q, DOUT * H / 4);
  quant_x_kernel<<<2048, 256, 0, stream>>>(x, xq0, a0_in, Bb * DIN / 4);

  gemm_i8_kernel<1><<<dim3(H / 128, Bb / 128), 256, 0, stream>>>(
      xq0, W0q, b0, xq1, Bb, H, DIN, a0_in, a0_w, a0_b, a2_in);
  gemm_i8_kernel<1><<<dim3(H / 128, Bb / 128), 256, 0, stream>>>(
      xq1, W2q, b2, xq2, Bb, H, H, a2_in, a2_w, a2_b, a4_in);
  gemm_i8_kernel<0><<<dim3(DOUT / 128, Bb / 128), 256, 0, stream>>>(
      xq2, W4q, b4, d_out, Bb, DOUT, H, a4_in, a4_w, a4_b, a4_in);
}

// Round 2
// 185.945 us; speedup vs baseline: 1.3292x; 1.3292x over previous
//
#include <hip/hip_runtime.h>

using i32x4 = __attribute__((ext_vector_type(4))) int;

#define DEVI static __device__ __forceinline__

DEVI void gload_lds16(const void* g, void* l) {
  __builtin_amdgcn_global_load_lds(
      (const __attribute__((address_space(1))) void*)g,
      (__attribute__((address_space(3))) void*)l, 16, 0, 0);
}

#define FENCE() asm volatile("" ::: "memory")
#define BARX()                        \
  do {                                \
    FENCE();                          \
    __builtin_amdgcn_s_barrier();     \
    FENCE();                          \
  } while (0)
#define LGKM0() asm volatile("s_waitcnt lgkmcnt(0)" ::: "memory")
#define VMC(n) asm volatile("s_waitcnt vmcnt(" #n ")" ::: "memory")
#define PRIO1() __builtin_amdgcn_s_setprio(1)
#define PRIO0() __builtin_amdgcn_s_setprio(0)

// ---------------- pack int32 weights -> int8 ----------------
__global__ void __launch_bounds__(256) pack_w_kernel(const int* __restrict__ w,
                                                     signed char* __restrict__ o,
                                                     int n4) {
  int stride = gridDim.x * blockDim.x;
  for (int i = blockIdx.x * blockDim.x + threadIdx.x; i < n4; i += stride) {
    int4 v = reinterpret_cast<const int4*>(w)[i];
    char4 c;
    c.x = (signed char)v.x;
    c.y = (signed char)v.y;
    c.z = (signed char)v.z;
    c.w = (signed char)v.w;
    reinterpret_cast<char4*>(o)[i] = c;
  }
}

// ---------------- quantize fp32 x -> int8 ----------------
__global__ void __launch_bounds__(256) quant_x_kernel(const float* __restrict__ x,
                                                      signed char* __restrict__ o,
                                                      const float* __restrict__ amax,
                                                      int n4) {
  const float s = 127.0f / amax[0];
  int stride = gridDim.x * blockDim.x;
  for (int i = blockIdx.x * blockDim.x + threadIdx.x; i < n4; i += stride) {
    float4 v = reinterpret_cast<const float4*>(x)[i];
    char4 c;
    float q;
    q = fminf(fmaxf(rintf(__fmul_rn(v.x, s)), -127.0f), 127.0f); c.x = (signed char)(int)q;
    q = fminf(fmaxf(rintf(__fmul_rn(v.y, s)), -127.0f), 127.0f); c.y = (signed char)(int)q;
    q = fminf(fmaxf(rintf(__fmul_rn(v.z, s)), -127.0f), 127.0f); c.z = (signed char)(int)q;
    q = fminf(fmaxf(rintf(__fmul_rn(v.w, s)), -127.0f), 127.0f); c.w = (signed char)(int)q;
    reinterpret_cast<char4*>(o)[i] = c;
  }
}

// ---------------- int8 GEMM, 256x(BN) 8-phase structure ----------------
// A: [M,K] i8 row-major; W: [N,K] i8 row-major. BM=256 fixed, BK=128 bytes.
// 8 waves (2M x 4N), per-wave C = 128 x (BN/4). Double-buffered LDS with
// XOR-swizzled 16B slots; counted vmcnt; setprio around MFMA clusters.

// staging: thread tid stages LDS slot (row = base+tid>>3, slot = tid&7) from
// global col16 = (tid&7) ^ ((tid>>3)&7)  (inverse swizzle on the SOURCE).
// issue order per K-tile: B[0..NN-1], A rows[0-63], A[128-191], A[64-127],
// A[192-255].  Phase0/1 need B* + A[0-63] + A[128-191]  -> vmcnt(2) suffices.
// Phase2/3 need the last two A issues                    -> vmcnt(0) at ph1 end.
#define STAGE(buf, kt)                                                          \
  do {                                                                          \
    const int k0_ = (kt) * 128 + scol;                                          \
    _Pragma("unroll") for (int j = 0; j < NN; ++j)                              \
        gload_lds16(Wb + (size_t)(j * 64 + srow) * K + k0_,                     \
                    &lds[buf][ABYTES + j * 8192 + tid * 16]);                   \
    gload_lds16(Ab + (size_t)(srow) * K + k0_, &lds[buf][tid * 16]);            \
    gload_lds16(Ab + (size_t)(128 + srow) * K + k0_, &lds[buf][16384 + tid * 16]); \
    gload_lds16(Ab + (size_t)(64 + srow) * K + k0_, &lds[buf][8192 + tid * 16]);   \
    gload_lds16(Ab + (size_t)(192 + srow) * K + k0_, &lds[buf][24576 + tid * 16]); \
  } while (0)

#define AF_(buf, m, h) \
  (*(const i32x4*)&lds[buf][(wrl + (m)*16 + ro) * 128 + ((h) ? cS1 : cS0)])
#define BF_(buf, n, h) \
  (*(const i32x4*)&lds[buf][ABYTES + (wcl + (n)*16 + ro) * 128 + ((h) ? cS1 : cS0)])

#define READ_AF(buf, m0)       \
  do {                         \
    af[0][0] = AF_(buf, m0, 0);      \
    af[0][1] = AF_(buf, m0, 1);      \
    af[1][0] = AF_(buf, (m0) + 1, 0); \
    af[1][1] = AF_(buf, (m0) + 1, 1); \
  } while (0)

#define READ_BF(buf)                               \
  do {                                             \
    _Pragma("unroll") for (int n = 0; n < NN; ++n) { \
      bf[n][0] = BF_(buf, n, 0);                   \
      bf[n][1] = BF_(buf, n, 1);                   \
    }                                              \
  } while (0)

#define MFMA_PAIR(mp)                                                                        \
  do {                                                                                       \
    _Pragma("unroll") for (int n = 0; n < NN; ++n) {                                         \
      acc[2 * (mp)][n] =                                                                     \
          __builtin_amdgcn_mfma_i32_16x16x64_i8(af[0][0], bf[n][0], acc[2 * (mp)][n], 0, 0, 0); \
      acc[2 * (mp)][n] =                                                                     \
          __builtin_amdgcn_mfma_i32_16x16x64_i8(af[0][1], bf[n][1], acc[2 * (mp)][n], 0, 0, 0); \
      acc[2 * (mp) + 1][n] = __builtin_amdgcn_mfma_i32_16x16x64_i8(af[1][0], bf[n][0],       \
                                                                   acc[2 * (mp) + 1][n], 0, 0, 0); \
      acc[2 * (mp) + 1][n] = __builtin_amdgcn_mfma_i32_16x16x64_i8(af[1][1], bf[n][1],       \
                                                                   acc[2 * (mp) + 1][n], 0, 0, 0); \
    }                                                                                        \
  } while (0)

#define TILE(buf, t)                                                     \
  do {                                                                   \
    READ_BF(buf);                                                        \
    READ_AF(buf, 0);                                                     \
    BARX(); LGKM0(); PRIO1(); MFMA_PAIR(0); PRIO0(); BARX();             \
    READ_AF(buf, 2);                                                     \
    BARX(); LGKM0(); PRIO1(); MFMA_PAIR(1); PRIO0(); VMC(0); BARX();     \
    if ((t) + 1 < nt) STAGE(1 - (buf), (t) + 1);                         \
    READ_AF(buf, 4);                                                     \
    BARX(); LGKM0(); PRIO1(); MFMA_PAIR(2); PRIO0(); BARX();             \
    READ_AF(buf, 6);                                                     \
    BARX(); LGKM0(); PRIO1(); MFMA_PAIR(3); PRIO0(); VMC(2); BARX();     \
  } while (0)

template <int BN, int OUT_I8>
__global__ __launch_bounds__(512, 2) void gemm8_kernel(
    const signed char* __restrict__ A, const signed char* __restrict__ W,
    const int* __restrict__ bias, void* __restrict__ out, int M, int N, int K,
    const float* __restrict__ p_ain, const float* __restrict__ p_aw,
    const float* __restrict__ p_ab, const float* __restrict__ p_anext) {
  static_assert(BN == 256 || BN == 128, "");
  constexpr int NN = BN / 64;          // n-frags per wave (and B stage issues)
  constexpr int ABYTES = 256 * 128;    // 32 KiB A-tile
  __shared__ signed char lds[2][ABYTES + BN * 128];

  const int tid = threadIdx.x;
  const int lane = tid & 63;
  const int wave = tid >> 6;
  const int wrl = (wave >> 2) * 128;        // wave row offset in 256
  const int wcl = (wave & 3) * (BN / 4);    // wave col offset in BN
  const int tileM = blockIdx.y * 256;
  const int tileN = blockIdx.x * BN;

  const signed char* Ab = A + (size_t)tileM * K;
  const signed char* Wb = W + (size_t)tileN * K;

  const int srow = tid >> 3;                       // staging row 0..63
  const int scol = ((tid & 7) ^ (srow & 7)) * 16;  // inverse-swizzled source col

  const int ro = lane & 15;   // fragment row within 16
  const int kg = lane >> 4;   // 16B k-group 0..3
  const int cS0 = ((kg ^ (ro & 7)) << 4);         // swizzled slot, k-half 0
  const int cS1 = (((4 + kg) ^ (ro & 7)) << 4);   // swizzled slot, k-half 1

  const int nt = K >> 7;      // K-tiles of 128 bytes

  i32x4 acc[8][NN] = {};
  i32x4 af[2][2], bf[NN][2];

  STAGE(0, 0);
  VMC(2);
  BARX();

  for (int t = 0; t < nt; t += 2) {
    TILE(0, t);
    TILE(1, t + 1);
  }

  // ---- epilogue: dequant + bias (+ relu + requant) ----
  const float s1 = __fmul_rn(p_aw[0], p_ain[0]) / 16129.0f;  // a_w*a_in/127^2
  const float s2 = p_ab[0] / 127.0f;                         // a_b/127
  float qs = 0.0f;
  if (OUT_I8) qs = 127.0f / p_anext[0];

#pragma unroll
  for (int m = 0; m < 8; ++m) {
#pragma unroll
    for (int n = 0; n < NN; ++n) {
      const int col = tileN + wcl + n * 16 + ro;
      const int row0 = tileM + wrl + m * 16 + kg * 4;
      const float bv = __fmul_rn((float)bias[col], s2);
#pragma unroll
      for (int i = 0; i < 4; ++i) {
        float y = __fadd_rn(__fmul_rn((float)acc[m][n][i], s1), bv);
        if (OUT_I8) {
          float rl = fmaxf(y, 0.0f);
          float q = fminf(rintf(__fmul_rn(rl, qs)), 127.0f);
          ((signed char*)out)[(size_t)(row0 + i) * N + col] = (signed char)(int)q;
        } else {
          ((float*)out)[(size_t)(row0 + i) * N + col] = y;
        }
      }
    }
  }
}

extern "C" void kernel_launch(void* const* d_in, const int* in_sizes, int n_in,
                              void* d_out, int out_size, void* d_ws, size_t ws_size,
                              hipStream_t stream) {
  const float* x = (const float*)d_in[0];
  const int* W0 = (const int*)d_in[1];
  const int* b0 = (const int*)d_in[2];
  const int* W2 = (const int*)d_in[3];
  const int* b2 = (const int*)d_in[4];
  const int* W4 = (const int*)d_in[5];
  const int* b4 = (const int*)d_in[6];
  const float* a0_in = (const float*)d_in[7];
  const float* a0_w = (const float*)d_in[8];
  const float* a0_b = (const float*)d_in[9];
  const float* a2_in = (const float*)d_in[10];
  const float* a2_w = (const float*)d_in[11];
  const float* a2_b = (const float*)d_in[12];
  const float* a4_in = (const float*)d_in[13];
  const float* a4_w = (const float*)d_in[14];
  const float* a4_b = (const float*)d_in[15];

  constexpr int Bb = 4096, DIN = 2048, H = 4096, DOUT = 2048;
  constexpr size_t MB = 1u << 20;

  char* ws = (char*)d_ws;
  signed char* xq0 = (signed char*)(ws);             //  8 MB  [0,8)
  signed char* xq2 = (signed char*)(ws);             // 16 MB  [0,16) (later; aliases xq0+W0q, dead then)
  signed char* W0q = (signed char*)(ws + 8 * MB);    //  8 MB  [8,16)
  signed char* W2q = (signed char*)(ws + 16 * MB);   // 16 MB  [16,32)
  signed char* W4q = (signed char*)(ws + 32 * MB);   //  8 MB  [32,40)
  signed char* xq1 = (signed char*)(ws + 40 * MB);   // 16 MB  [40,56)

  pack_w_kernel<<<2048, 256, 0, stream>>>(W0, W0q, H * DIN / 4);
  pack_w_kernel<<<2048, 256, 0, stream>>>(W2, W2q, H * H / 4);
  pack_w_kernel<<<2048, 256, 0, stream>>>(W4, W4q, DOUT * H / 4);
  quant_x_kernel<<<2048, 256, 0, stream>>>(x, xq0, a0_in, Bb * DIN / 4);

  gemm8_kernel<256, 1><<<dim3(H / 256, Bb / 256), 512, 0, stream>>>(
      xq0, W0q, b0, xq1, Bb, H, DIN, a0_in, a0_w, a0_b, a2_in);
  gemm8_kernel<256, 1><<<dim3(H / 256, Bb / 256), 512, 0, stream>>>(
      xq1, W2q, b2, xq2, Bb, H, H, a2_in, a2_w, a2_b, a4_in);
  gemm8_kernel<128, 0><<<dim3(DOUT / 128, Bb / 256), 512, 0, stream>>>(
      xq2, W4q, b4, d_out, Bb, DOUT, H, a4_in, a4_w, a4_b, a4_in);
}

// Round 3
// 171.477 us; speedup vs baseline: 1.4413x; 1.0844x over previous
//
#include <hip/hip_runtime.h>

using i32x4 = __attribute__((ext_vector_type(4))) int;

#define DEVI static __device__ __forceinline__

DEVI void gload_lds16(const void* g, void* l) {
  __builtin_amdgcn_global_load_lds(
      (const __attribute__((address_space(1))) void*)g,
      (__attribute__((address_space(3))) void*)l, 16, 0, 0);
}

template <int N> DEVI void vmcnt_n() {
  asm volatile("s_waitcnt vmcnt(%0)" ::"n"(N) : "memory");
}
template <int N> DEVI void lgkm_n() {
  asm volatile("s_waitcnt lgkmcnt(%0)" ::"n"(N) : "memory");
}

#define FENCE() asm volatile("" ::: "memory")
#define BARX()                    \
  do {                            \
    FENCE();                      \
    __builtin_amdgcn_s_barrier(); \
    FENCE();                      \
  } while (0)
#define SCHB() __builtin_amdgcn_sched_barrier(0)
#define PRIO1() __builtin_amdgcn_s_setprio(1)
#define PRIO0() __builtin_amdgcn_s_setprio(0)

// ---------------- pack int32 weights -> int8 ----------------
__global__ void __launch_bounds__(256) pack_w_kernel(const int* __restrict__ w,
                                                     signed char* __restrict__ o,
                                                     int n4) {
  int stride = gridDim.x * blockDim.x;
  for (int i = blockIdx.x * blockDim.x + threadIdx.x; i < n4; i += stride) {
    int4 v = reinterpret_cast<const int4*>(w)[i];
    char4 c;
    c.x = (signed char)v.x;
    c.y = (signed char)v.y;
    c.z = (signed char)v.z;
    c.w = (signed char)v.w;
    reinterpret_cast<char4*>(o)[i] = c;
  }
}

// ---------------- quantize fp32 x -> int8 ----------------
__global__ void __launch_bounds__(256) quant_x_kernel(const float* __restrict__ x,
                                                      signed char* __restrict__ o,
                                                      const float* __restrict__ amax,
                                                      int n4) {
  const float s = 127.0f / amax[0];
  int stride = gridDim.x * blockDim.x;
  for (int i = blockIdx.x * blockDim.x + threadIdx.x; i < n4; i += stride) {
    float4 v = reinterpret_cast<const float4*>(x)[i];
    char4 c;
    float q;
    q = fminf(fmaxf(rintf(__fmul_rn(v.x, s)), -127.0f), 127.0f); c.x = (signed char)(int)q;
    q = fminf(fmaxf(rintf(__fmul_rn(v.y, s)), -127.0f), 127.0f); c.y = (signed char)(int)q;
    q = fminf(fmaxf(rintf(__fmul_rn(v.z, s)), -127.0f), 127.0f); c.z = (signed char)(int)q;
    q = fminf(fmaxf(rintf(__fmul_rn(v.w, s)), -127.0f), 127.0f); c.w = (signed char)(int)q;
    reinterpret_cast<char4*>(o)[i] = c;
  }
}

// ---------------- int8 GEMM, 256xBN, pipelined 4-window schedule ----------
// A: [M,K] i8 row-major; W: [N,K] i8 row-major. BK = 128 bytes.
// 8 waves (2M x 4N), per-wave C = 128 x (BN/4). Double-buffered XOR-swizzled
// LDS; register frags pipelined one window ahead; counted vmcnt/lgkmcnt
// (never 0 in steady state); 1 barrier per window; setprio around MFMA.

// stage helpers: thread tid covers row srow=tid>>3, slot tid&7; the global
// source column is inverse-swizzled so a swizzled LDS read sees linear data.
#define GB(b, j, k0_)                                           \
  gload_lds16(Wb + (size_t)((j)*64 + srow) * K + (k0_),         \
              &lds[b][ABYTES + (j)*8192 + tid * 16])
#define GA(b, r0, k0_)                                          \
  gload_lds16(Ab + (size_t)((r0) + srow) * K + (k0_),           \
              &lds[b][(r0)*128 + tid * 16])

#define STG_B(b, kt)                               \
  do {                                             \
    const int k0_ = (kt)*128 + scol;               \
    _Pragma("unroll") for (int j = 0; j < NN; ++j) GB(b, j, k0_); \
  } while (0)
#define STG_A(b, kt)                 \
  do {                               \
    const int k0_ = (kt)*128 + scol; \
    GA(b, 0, k0_);                   \
    GA(b, 128, k0_);                 \
    GA(b, 64, k0_);                  \
    GA(b, 192, k0_);                 \
  } while (0)

#define AF_(b, m, h) \
  (*(const i32x4*)&lds[b][(wrl + (m)*16 + ro) * 128 + ((h) ? cS1 : cS0)])
#define BF_(b, n, h) \
  (*(const i32x4*)&lds[b][ABYTES + (wcl + (n)*16 + ro) * 128 + ((h) ? cS1 : cS0)])

#define RD_AF(dst, b, m0)          \
  do {                             \
    dst[0][0] = AF_(b, m0, 0);     \
    dst[0][1] = AF_(b, m0, 1);     \
    dst[1][0] = AF_(b, (m0) + 1, 0); \
    dst[1][1] = AF_(b, (m0) + 1, 1); \
  } while (0)

#define READ_BF(b)                                   \
  do {                                               \
    _Pragma("unroll") for (int n = 0; n < NN; ++n) { \
      bf[n][0] = BF_(b, n, 0);                       \
      bf[n][1] = BF_(b, n, 1);                       \
    }                                                \
  } while (0)

#define MFMA_P(mp, af)                                                                     \
  do {                                                                                     \
    _Pragma("unroll") for (int n = 0; n < NN; ++n) {                                       \
      acc[2 * (mp)][n] =                                                                   \
          __builtin_amdgcn_mfma_i32_16x16x64_i8(af[0][0], bf[n][0], acc[2 * (mp)][n], 0, 0, 0); \
      acc[2 * (mp)][n] =                                                                   \
          __builtin_amdgcn_mfma_i32_16x16x64_i8(af[0][1], bf[n][1], acc[2 * (mp)][n], 0, 0, 0); \
      acc[2 * (mp) + 1][n] = __builtin_amdgcn_mfma_i32_16x16x64_i8(                        \
          af[1][0], bf[n][0], acc[2 * (mp) + 1][n], 0, 0, 0);                              \
      acc[2 * (mp) + 1][n] = __builtin_amdgcn_mfma_i32_16x16x64_i8(                        \
          af[1][1], bf[n][1], acc[2 * (mp) + 1][n], 0, 0, 0);                              \
    }                                                                                      \
  } while (0)

// steady-state tile: reads for window w+1 issued in window w's front (pre-
// barrier); stage B(t+1) at p0, A(t+1) at p1; vmcnt VM0 at p0 covers
// A64/A192(t) for the p1/p2 reads, vmcnt(2) at p2 covers B+A0/A128(t+1).
#define TILE_STEADY(b, t)                       \
  do {                                          \
    READ_BF(b);                                 \
    RD_AF(afB, b, 2);                           \
    STG_B(1 - (b), (t) + 1);                    \
    vmcnt_n<VM0>();                             \
    BARX(); lgkm_n<4>(); SCHB();                \
    PRIO1(); MFMA_P(0, afA); PRIO0();           \
    RD_AF(afA, b, 4);                           \
    STG_A(1 - (b), (t) + 1);                    \
    BARX(); lgkm_n<4>(); SCHB();                \
    PRIO1(); MFMA_P(1, afB); PRIO0();           \
    RD_AF(afB, b, 6);                           \
    vmcnt_n<2>();                               \
    BARX(); lgkm_n<4>(); SCHB();                \
    PRIO1(); MFMA_P(2, afA); PRIO0();           \
    RD_AF(afA, 1 - (b), 0);                     \
    BARX(); lgkm_n<4>(); SCHB();                \
    PRIO1(); MFMA_P(3, afB); PRIO0();           \
  } while (0)

#define TILE_LAST(b)                            \
  do {                                          \
    READ_BF(b);                                 \
    RD_AF(afB, b, 2);                           \
    vmcnt_n<0>();                               \
    BARX(); lgkm_n<4>(); SCHB();                \
    PRIO1(); MFMA_P(0, afA); PRIO0();           \
    RD_AF(afA, b, 4);                           \
    BARX(); lgkm_n<4>(); SCHB();                \
    PRIO1(); MFMA_P(1, afB); PRIO0();           \
    RD_AF(afB, b, 6);                           \
    BARX(); lgkm_n<4>(); SCHB();                \
    PRIO1(); MFMA_P(2, afA); PRIO0();           \
    BARX(); lgkm_n<0>(); SCHB();                \
    PRIO1(); MFMA_P(3, afB); PRIO0();           \
  } while (0)

template <int BN, int OUT_I8>
__global__ __launch_bounds__(512, 2) void gemm8_kernel(
    const signed char* __restrict__ A, const signed char* __restrict__ W,
    const int* __restrict__ bias, void* __restrict__ out, int M, int N, int K,
    const float* __restrict__ p_ain, const float* __restrict__ p_aw,
    const float* __restrict__ p_ab, const float* __restrict__ p_anext) {
  static_assert(BN == 256 || BN == 128, "");
  constexpr int NN = BN / 64;
  constexpr int VM0 = (NN == 4) ? 4 : 2;
  constexpr int ABYTES = 256 * 128;  // 32 KiB A-tile
  __shared__ signed char lds[2][ABYTES + BN * 128];

  const int tid = threadIdx.x;
  const int lane = tid & 63;
  const int wave = tid >> 6;
  const int wrl = (wave >> 2) * 128;      // wave row offset in 256
  const int wcl = (wave & 3) * (BN / 4);  // wave col offset in BN
  const int tileM = blockIdx.y * 256;
  const int tileN = blockIdx.x * BN;

  const signed char* Ab = A + (size_t)tileM * K;
  const signed char* Wb = W + (size_t)tileN * K;

  const int srow = tid >> 3;                       // staging row 0..63
  const int scol = ((tid & 7) ^ (srow & 7)) * 16;  // inverse-swizzled src col

  const int ro = lane & 15;  // fragment row within 16
  const int kg = lane >> 4;  // 16B k-group 0..3
  const int cS0 = ((kg ^ (ro & 7)) << 4);        // swizzled slot, k-half 0
  const int cS1 = (((4 + kg) ^ (ro & 7)) << 4);  // swizzled slot, k-half 1

  const int nt = K >> 7;  // K-tiles of 128 bytes

  i32x4 acc[8][NN] = {};
  i32x4 afA[2][2], afB[2][2], bf[NN][2];

  // prologue: stage tile 0 (order B0..B(NN-1), A0, A128, A64, A192)
  STG_B(0, 0);
  STG_A(0, 0);
  vmcnt_n<2>();  // B + A0 + A128 done; A64/A192 stay in flight
  BARX();
  RD_AF(afA, 0, 0);

  for (int t = 0; t < nt - 2; t += 2) {
    TILE_STEADY(0, t);
    TILE_STEADY(1, t + 1);
  }
  TILE_STEADY(0, nt - 2);
  TILE_LAST(1);

  // ---- epilogue: dequant + bias (+ relu + requant) ----
  const float s1 = __fmul_rn(p_aw[0], p_ain[0]) / 16129.0f;  // a_w*a_in/127^2
  const float s2 = p_ab[0] / 127.0f;                         // a_b/127
  float qs = 0.0f;
  if (OUT_I8) qs = 127.0f / p_anext[0];

#pragma unroll
  for (int m = 0; m < 8; ++m) {
#pragma unroll
    for (int n = 0; n < NN; ++n) {
      const int col = tileN + wcl + n * 16 + ro;
      const int row0 = tileM + wrl + m * 16 + kg * 4;
      const float bv = __fmul_rn((float)bias[col], s2);
#pragma unroll
      for (int i = 0; i < 4; ++i) {
        float y = __fadd_rn(__fmul_rn((float)acc[m][n][i], s1), bv);
        if (OUT_I8) {
          float rl = fmaxf(y, 0.0f);
          float q = fminf(rintf(__fmul_rn(rl, qs)), 127.0f);
          ((signed char*)out)[(size_t)(row0 + i) * N + col] = (signed char)(int)q;
        } else {
          ((float*)out)[(size_t)(row0 + i) * N + col] = y;
        }
      }
    }
  }
}

extern "C" void kernel_launch(void* const* d_in, const int* in_sizes, int n_in,
                              void* d_out, int out_size, void* d_ws, size_t ws_size,
                              hipStream_t stream) {
  const float* x = (const float*)d_in[0];
  const int* W0 = (const int*)d_in[1];
  const int* b0 = (const int*)d_in[2];
  const int* W2 = (const int*)d_in[3];
  const int* b2 = (const int*)d_in[4];
  const int* W4 = (const int*)d_in[5];
  const int* b4 = (const int*)d_in[6];
  const float* a0_in = (const float*)d_in[7];
  const float* a0_w = (const float*)d_in[8];
  const float* a0_b = (const float*)d_in[9];
  const float* a2_in = (const float*)d_in[10];
  const float* a2_w = (const float*)d_in[11];
  const float* a2_b = (const float*)d_in[12];
  const float* a4_in = (const float*)d_in[13];
  const float* a4_w = (const float*)d_in[14];
  const float* a4_b = (const float*)d_in[15];

  constexpr int Bb = 4096, DIN = 2048, H = 4096, DOUT = 2048;
  constexpr size_t MB = 1u << 20;

  char* ws = (char*)d_ws;
  signed char* xq0 = (signed char*)(ws);           //  8 MB  [0,8)
  signed char* xq2 = (signed char*)(ws);           // 16 MB  [0,16) (aliases xq0+W0q, dead then)
  signed char* W0q = (signed char*)(ws + 8 * MB);  //  8 MB  [8,16)
  signed char* W2q = (signed char*)(ws + 16 * MB); // 16 MB  [16,32)
  signed char* W4q = (signed char*)(ws + 32 * MB); //  8 MB  [32,40)
  signed char* xq1 = (signed char*)(ws + 40 * MB); // 16 MB  [40,56)

  pack_w_kernel<<<2048, 256, 0, stream>>>(W0, W0q, H * DIN / 4);
  pack_w_kernel<<<2048, 256, 0, stream>>>(W2, W2q, H * H / 4);
  pack_w_kernel<<<2048, 256, 0, stream>>>(W4, W4q, DOUT * H / 4);
  quant_x_kernel<<<2048, 256, 0, stream>>>(x, xq0, a0_in, Bb * DIN / 4);

  gemm8_kernel<256, 1><<<dim3(H / 256, Bb / 256), 512, 0, stream>>>(
      xq0, W0q, b0, xq1, Bb, H, DIN, a0_in, a0_w, a0_b, a2_in);
  gemm8_kernel<256, 1><<<dim3(H / 256, Bb / 256), 512, 0, stream>>>(
      xq1, W2q, b2, xq2, Bb, H, H, a2_in, a2_w, a2_b, a4_in);
  gemm8_kernel<128, 0><<<dim3(DOUT / 128, Bb / 256), 512, 0, stream>>>(
      xq2, W4q, b4, d_out, Bb, DOUT, H, a4_in, a4_w, a4_b, a4_in);
}

// Round 4
// 166.395 us; speedup vs baseline: 1.4853x; 1.0305x over previous
//
#include <hip/hip_runtime.h>

using i32x4 = __attribute__((ext_vector_type(4))) int;

#define DEVI static __device__ __forceinline__

DEVI void gload_lds16(const void* g, void* l) {
  __builtin_amdgcn_global_load_lds(
      (const __attribute__((address_space(1))) void*)g,
      (__attribute__((address_space(3))) void*)l, 16, 0, 0);
}

template <int N> DEVI void vmcnt_n() {
  asm volatile("s_waitcnt vmcnt(%0)" ::"n"(N) : "memory");
}
template <int N> DEVI void lgkm_n() {
  asm volatile("s_waitcnt lgkmcnt(%0)" ::"n"(N) : "memory");
}

#define FENCE() asm volatile("" ::: "memory")
#define BARX()                    \
  do {                            \
    FENCE();                      \
    __builtin_amdgcn_s_barrier(); \
    FENCE();                      \
  } while (0)
#define SCHB() __builtin_amdgcn_sched_barrier(0)
#define PRIO1() __builtin_amdgcn_s_setprio(1)
#define PRIO0() __builtin_amdgcn_s_setprio(0)

// ---------------- pack int32 weights -> int8 ----------------
__global__ void __launch_bounds__(256) pack_w_kernel(const int* __restrict__ w,
                                                     signed char* __restrict__ o,
                                                     int n4) {
  int stride = gridDim.x * blockDim.x;
  for (int i = blockIdx.x * blockDim.x + threadIdx.x; i < n4; i += stride) {
    int4 v = reinterpret_cast<const int4*>(w)[i];
    char4 c;
    c.x = (signed char)v.x;
    c.y = (signed char)v.y;
    c.z = (signed char)v.z;
    c.w = (signed char)v.w;
    reinterpret_cast<char4*>(o)[i] = c;
  }
}

// ---------------- quantize fp32 x -> int8 ----------------
__global__ void __launch_bounds__(256) quant_x_kernel(const float* __restrict__ x,
                                                      signed char* __restrict__ o,
                                                      const float* __restrict__ amax,
                                                      int n4) {
  const float s = 127.0f / amax[0];
  int stride = gridDim.x * blockDim.x;
  for (int i = blockIdx.x * blockDim.x + threadIdx.x; i < n4; i += stride) {
    float4 v = reinterpret_cast<const float4*>(x)[i];
    char4 c;
    float q;
    q = fminf(fmaxf(rintf(__fmul_rn(v.x, s)), -127.0f), 127.0f); c.x = (signed char)(int)q;
    q = fminf(fmaxf(rintf(__fmul_rn(v.y, s)), -127.0f), 127.0f); c.y = (signed char)(int)q;
    q = fminf(fmaxf(rintf(__fmul_rn(v.z, s)), -127.0f), 127.0f); c.z = (signed char)(int)q;
    q = fminf(fmaxf(rintf(__fmul_rn(v.w, s)), -127.0f), 127.0f); c.w = (signed char)(int)q;
    reinterpret_cast<char4*>(o)[i] = c;
  }
}

// ---------------- int8 GEMM, 256xBN, pipelined 4-window schedule ----------
// A: [M,K] i8 row-major; W: [N,K] i8 row-major. BK = 128 bytes.
// 8 waves (2M x 4N), per-wave C = 128 x (BN/4). Double-buffered XOR-swizzled
// LDS; register frags pipelined one window ahead; stage issues SPREAD so the
// youngest load has >=2 windows before its validity vmcnt:
//   B[0..NBE-1](t+1) at p3(t-1); B[NBE..NN-1]+A0+A128(t+1) at p0(t);
//   A64+A192(t+1) at p1(t).
// vmcnt(NN+2) at p0 retires A64/A192(t); vmcnt(2) at p2 retires B+A0/A128(t+1).

#define GB(b, j, k0_)                                           \
  gload_lds16(Wb + (size_t)((j)*64 + srow) * K + (k0_),         \
              &lds[b][ABYTES + (j)*8192 + tid * 16])
#define GA(b, r0, k0_)                                          \
  gload_lds16(Ab + (size_t)((r0) + srow) * K + (k0_),           \
              &lds[b][(r0)*128 + tid * 16])

#define STG_B_EARLY(b, kt)                                              \
  do {                                                                  \
    const int k0_ = (kt)*128 + scol;                                    \
    _Pragma("unroll") for (int j = 0; j < NBE; ++j) GB(b, j, k0_);      \
  } while (0)
#define STG_B_LATE(b, kt)                                               \
  do {                                                                  \
    const int k0_ = (kt)*128 + scol;                                    \
    _Pragma("unroll") for (int j = NBE; j < NN; ++j) GB(b, j, k0_);     \
  } while (0)
#define STG_A01(b, kt)               \
  do {                               \
    const int k0_ = (kt)*128 + scol; \
    GA(b, 0, k0_);                   \
    GA(b, 128, k0_);                 \
  } while (0)
#define STG_A23(b, kt)               \
  do {                               \
    const int k0_ = (kt)*128 + scol; \
    GA(b, 64, k0_);                  \
    GA(b, 192, k0_);                 \
  } while (0)

#define AF_(b, m, h) \
  (*(const i32x4*)&lds[b][(wrl + (m)*16 + ro) * 128 + ((h) ? cS1 : cS0)])
#define BF_(b, n, h) \
  (*(const i32x4*)&lds[b][ABYTES + (wcl + (n)*16 + ro) * 128 + ((h) ? cS1 : cS0)])

#define RD_AF(dst, b, m0)            \
  do {                               \
    dst[0][0] = AF_(b, m0, 0);       \
    dst[0][1] = AF_(b, m0, 1);       \
    dst[1][0] = AF_(b, (m0) + 1, 0); \
    dst[1][1] = AF_(b, (m0) + 1, 1); \
  } while (0)

#define READ_BF(b)                                   \
  do {                                               \
    _Pragma("unroll") for (int n = 0; n < NN; ++n) { \
      bf[n][0] = BF_(b, n, 0);                       \
      bf[n][1] = BF_(b, n, 1);                       \
    }                                                \
  } while (0)

#define MFMA_P(mp, af)                                                                     \
  do {                                                                                     \
    _Pragma("unroll") for (int n = 0; n < NN; ++n) {                                       \
      acc[2 * (mp)][n] =                                                                   \
          __builtin_amdgcn_mfma_i32_16x16x64_i8(af[0][0], bf[n][0], acc[2 * (mp)][n], 0, 0, 0); \
      acc[2 * (mp)][n] =                                                                   \
          __builtin_amdgcn_mfma_i32_16x16x64_i8(af[0][1], bf[n][1], acc[2 * (mp)][n], 0, 0, 0); \
      acc[2 * (mp) + 1][n] = __builtin_amdgcn_mfma_i32_16x16x64_i8(                        \
          af[1][0], bf[n][0], acc[2 * (mp) + 1][n], 0, 0, 0);                              \
      acc[2 * (mp) + 1][n] = __builtin_amdgcn_mfma_i32_16x16x64_i8(                        \
          af[1][1], bf[n][1], acc[2 * (mp) + 1][n], 0, 0, 0);                              \
    }                                                                                      \
  } while (0)

#define TILE_STEADY(b, t)                       \
  do {                                          \
    READ_BF(b);                                 \
    RD_AF(afB, b, 2);                           \
    STG_B_LATE(1 - (b), (t) + 1);               \
    STG_A01(1 - (b), (t) + 1);                  \
    vmcnt_n<NN + 2>();                          \
    BARX(); lgkm_n<4>(); SCHB();                \
    PRIO1(); MFMA_P(0, afA); PRIO0();           \
    RD_AF(afA, b, 4);                           \
    STG_A23(1 - (b), (t) + 1);                  \
    BARX(); lgkm_n<4>(); SCHB();                \
    PRIO1(); MFMA_P(1, afB); PRIO0();           \
    RD_AF(afB, b, 6);                           \
    vmcnt_n<2>();                               \
    BARX(); lgkm_n<4>(); SCHB();                \
    PRIO1(); MFMA_P(2, afA); PRIO0();           \
    RD_AF(afA, 1 - (b), 0);                     \
    if ((t) + 2 < nt) STG_B_EARLY(b, (t) + 2);  \
    BARX(); lgkm_n<4>(); SCHB();                \
    PRIO1(); MFMA_P(3, afB); PRIO0();           \
  } while (0)

#define TILE_LAST(b)                            \
  do {                                          \
    READ_BF(b);                                 \
    RD_AF(afB, b, 2);                           \
    vmcnt_n<0>();                               \
    BARX(); lgkm_n<4>(); SCHB();                \
    PRIO1(); MFMA_P(0, afA); PRIO0();           \
    RD_AF(afA, b, 4);                           \
    BARX(); lgkm_n<4>(); SCHB();                \
    PRIO1(); MFMA_P(1, afB); PRIO0();           \
    RD_AF(afB, b, 6);                           \
    BARX(); lgkm_n<4>(); SCHB();                \
    PRIO1(); MFMA_P(2, afA); PRIO0();           \
    BARX(); lgkm_n<0>(); SCHB();                \
    PRIO1(); MFMA_P(3, afB); PRIO0();           \
  } while (0)

template <int BN, int OUT_I8>
__global__ __launch_bounds__(512, 2) void gemm8_kernel(
    const signed char* __restrict__ A, const signed char* __restrict__ W,
    const int* __restrict__ bias, void* __restrict__ out, int M, int N, int K,
    const float* __restrict__ p_ain, const float* __restrict__ p_aw,
    const float* __restrict__ p_ab, const float* __restrict__ p_anext) {
  static_assert(BN == 256 || BN == 128, "");
  constexpr int NN = BN / 64;
  constexpr int NBE = NN / 2;        // B loads issued one tile early (p3)
  constexpr int ABYTES = 256 * 128;  // 32 KiB A-tile
  __shared__ signed char lds[2][ABYTES + BN * 128];

  const int tid = threadIdx.x;
  const int lane = tid & 63;
  const int wave = tid >> 6;
  const int wrl = (wave >> 2) * 128;      // wave row offset in 256
  const int wcl = (wave & 3) * (BN / 4);  // wave col offset in BN
  const int tileM = blockIdx.y * 256;
  const int tileN = blockIdx.x * BN;

  const signed char* Ab = A + (size_t)tileM * K;
  const signed char* Wb = W + (size_t)tileN * K;

  const int srow = tid >> 3;                       // staging row 0..63
  const int scol = ((tid & 7) ^ (srow & 7)) * 16;  // inverse-swizzled src col

  const int ro = lane & 15;  // fragment row within 16
  const int kg = lane >> 4;  // 16B k-group 0..3
  const int cS0 = ((kg ^ (ro & 7)) << 4);        // swizzled slot, k-half 0
  const int cS1 = (((4 + kg) ^ (ro & 7)) << 4);  // swizzled slot, k-half 1

  const int nt = K >> 7;  // K-tiles of 128 bytes

  i32x4 acc[8][NN] = {};
  i32x4 afA[2][2], afB[2][2], bf[NN][2];

  // prologue: stage all of tile 0, then the early-B of tile 1
  {
    const int k0_ = scol;
#pragma unroll
    for (int j = 0; j < NN; ++j) GB(0, j, k0_);
    GA(0, 0, k0_);
    GA(0, 128, k0_);
    GA(0, 64, k0_);
    GA(0, 192, k0_);
  }
  FENCE();
  STG_B_EARLY(1, 1);
  vmcnt_n<NBE>();  // retire every tile-0 load; leave early-B(1) in flight
  BARX();
  RD_AF(afA, 0, 0);

  for (int t = 0; t < nt - 2; t += 2) {
    TILE_STEADY(0, t);
    TILE_STEADY(1, t + 1);
  }
  TILE_STEADY(0, nt - 2);
  TILE_LAST(1);

  // ---- epilogue: dequant + bias (+ relu + requant) ----
  const float s1 = __fmul_rn(p_aw[0], p_ain[0]) / 16129.0f;  // a_w*a_in/127^2
  const float s2 = p_ab[0] / 127.0f;                         // a_b/127
  float qs = 0.0f;
  if (OUT_I8) qs = 127.0f / p_anext[0];

#pragma unroll
  for (int m = 0; m < 8; ++m) {
#pragma unroll
    for (int n = 0; n < NN; ++n) {
      const int col = tileN + wcl + n * 16 + ro;
      const int row0 = tileM + wrl + m * 16 + kg * 4;
      const float bv = __fmul_rn((float)bias[col], s2);
#pragma unroll
      for (int i = 0; i < 4; ++i) {
        float y = __fadd_rn(__fmul_rn((float)acc[m][n][i], s1), bv);
        if (OUT_I8) {
          float rl = fmaxf(y, 0.0f);
          float q = fminf(rintf(__fmul_rn(rl, qs)), 127.0f);
          ((signed char*)out)[(size_t)(row0 + i) * N + col] = (signed char)(int)q;
        } else {
          ((float*)out)[(size_t)(row0 + i) * N + col] = y;
        }
      }
    }
  }
}

extern "C" void kernel_launch(void* const* d_in, const int* in_sizes, int n_in,
                              void* d_out, int out_size, void* d_ws, size_t ws_size,
                              hipStream_t stream) {
  const float* x = (const float*)d_in[0];
  const int* W0 = (const int*)d_in[1];
  const int* b0 = (const int*)d_in[2];
  const int* W2 = (const int*)d_in[3];
  const int* b2 = (const int*)d_in[4];
  const int* W4 = (const int*)d_in[5];
  const int* b4 = (const int*)d_in[6];
  const float* a0_in = (const float*)d_in[7];
  const float* a0_w = (const float*)d_in[8];
  const float* a0_b = (const float*)d_in[9];
  const float* a2_in = (const float*)d_in[10];
  const float* a2_w = (const float*)d_in[11];
  const float* a2_b = (const float*)d_in[12];
  const float* a4_in = (const float*)d_in[13];
  const float* a4_w = (const float*)d_in[14];
  const float* a4_b = (const float*)d_in[15];

  constexpr int Bb = 4096, DIN = 2048, H = 4096, DOUT = 2048;
  constexpr size_t MB = 1u << 20;

  char* ws = (char*)d_ws;
  signed char* xq0 = (signed char*)(ws);           //  8 MB  [0,8)
  signed char* xq2 = (signed char*)(ws);           // 16 MB  [0,16) (aliases xq0+W0q, dead then)
  signed char* W0q = (signed char*)(ws + 8 * MB);  //  8 MB  [8,16)
  signed char* W2q = (signed char*)(ws + 16 * MB); // 16 MB  [16,32)
  signed char* W4q = (signed char*)(ws + 32 * MB); //  8 MB  [32,40)
  signed char* xq1 = (signed char*)(ws + 40 * MB); // 16 MB  [40,56)

  pack_w_kernel<<<2048, 256, 0, stream>>>(W0, W0q, H * DIN / 4);
  pack_w_kernel<<<2048, 256, 0, stream>>>(W2, W2q, H * H / 4);
  pack_w_kernel<<<2048, 256, 0, stream>>>(W4, W4q, DOUT * H / 4);
  quant_x_kernel<<<2048, 256, 0, stream>>>(x, xq0, a0_in, Bb * DIN / 4);

  gemm8_kernel<256, 1><<<dim3(H / 256, Bb / 256), 512, 0, stream>>>(
      xq0, W0q, b0, xq1, Bb, H, DIN, a0_in, a0_w, a0_b, a2_in);
  gemm8_kernel<256, 1><<<dim3(H / 256, Bb / 256), 512, 0, stream>>>(
      xq1, W2q, b2, xq2, Bb, H, H, a2_in, a2_w, a2_b, a4_in);
  gemm8_kernel<128, 0><<<dim3(DOUT / 128, Bb / 256), 512, 0, stream>>>(
      xq2, W4q, b4, d_out, Bb, DOUT, H, a4_in, a4_w, a4_b, a4_in);
}